// Round 6
// baseline (210.936 us; speedup 1.0000x reference)
//
#include <hip/hip_runtime.h>
#include <math.h>

#define DIMH 256        // D
#define NB   32         // batch
#define E_TOT 43234
#define TE   64         // entities per block
#define DK   32         // d-chunk staged in LDS
#define DQ   128        // d-range per block in split mode
// reference: phase = rel / (REL_RANGE/PI); REL_RANGE/PI = 0.03125/PI
#define PHASE_DIV 0.009947183943243459f

typedef float v2f __attribute__((ext_vector_type(2)));
typedef float v4f __attribute__((ext_vector_type(4)));

// Kernel 1: rotate head by relation phase (fp32 sincosf).
__global__ void rot_kernel(const float* __restrict__ head,
                           const float* __restrict__ rel,
                           float* __restrict__ rot) {
    int i = blockIdx.x * blockDim.x + threadIdx.x;   // 0..8191
    int b = i >> 8;
    int d = i & 255;
    float re_h = head[b * 2 * DIMH + d];
    float im_h = head[b * 2 * DIMH + DIMH + d];
    float ph = rel[b * DIMH + d] / PHASE_DIV;
    float s, c;
    sincosf(ph, &s, &c);
    rot[b * DIMH + d]             = re_h * c - im_h * s;   // re_rot
    rot[NB * DIMH + b * DIMH + d] = re_h * s + im_h * c;   // im_rot
}

__device__ __forceinline__ v2f sqrt2(v2f s) {
    v2f r;
    r.x = __builtin_amdgcn_sqrtf(s.x);
    r.y = __builtin_amdgcn_sqrtf(s.y);
    return r;
}

// Kernel 2: block = 64-entity tile x (split: 128-d half | direct: all 256 d),
// all 32 batches. LDS element = float4 (re_d, re_d+1, im_d, im_d+1); row
// stride 17 float4 -> b128 reads conflict-free per 8-lane phase.
// LDS = 26.1 KB -> 6 blocks/CU = 24 waves/CU. Register prefetch of next chunk.
// Per-thread register tile: 4 batch x 2 entity.
// SPLIT mode: contention-free partial writes to ws (NO atomics — R5 showed
// cross-XCD atomic RMW turns 11 MB of results into 200+ MB of HBM traffic).
template<bool DIRECT>
__global__ __launch_bounds__(256, 6) void dist_kernel(const float* __restrict__ ent,
                                                      const float* __restrict__ rot,
                                                      float* __restrict__ dst) {
    __shared__ v4f s_e[TE][DK / 2 + 1];   // 64 x 17 float4 = 17.4 KB
    __shared__ v4f s_r[NB][DK / 2 + 1];   // 32 x 17 float4 =  8.7 KB

    const int tid   = threadIdx.x;
    const int etile = DIRECT ? blockIdx.x : (blockIdx.x >> 1);
    const int half  = DIRECT ? 0 : (blockIdx.x & 1);
    const int NC    = DIRECT ? (DIMH / DK) : (DQ / DK);
    const int eb    = etile * TE;
    const int eg    = tid & 31;          // entity group: rows eg, eg+32
    const int bg    = (tid >> 5) * 4;    // first of 4 batch rows
    const int dbase = half * DQ;

    // staging decomposition (per thread):
    //   ent: 512 items, 2/thread: row = q>>3 (0..63), c4 = q&7
    //   rot: 256 items, 1/thread: row = tid>>3,       c4 = tid&7
    const int er0 = min(eb + (tid >> 3), E_TOT - 1);
    const int er1 = min(eb + ((tid + 256) >> 3), E_TOT - 1);
    const int ec0 = (tid & 7) << 2;
    const int rrow = tid >> 3;

    float4 pe_re[2], pe_im[2], p_rr, p_ri;

    auto load_chunk = [&](int dk) {
        const float* b0 = &ent[(size_t)er0 * (2 * DIMH)];
        const float* b1 = &ent[(size_t)er1 * (2 * DIMH)];
        pe_re[0] = *reinterpret_cast<const float4*>(b0 + dk + ec0);
        pe_im[0] = *reinterpret_cast<const float4*>(b0 + DIMH + dk + ec0);
        pe_re[1] = *reinterpret_cast<const float4*>(b1 + dk + ec0);
        pe_im[1] = *reinterpret_cast<const float4*>(b1 + DIMH + dk + ec0);
        p_rr = *reinterpret_cast<const float4*>(&rot[rrow * DIMH + dk + ec0]);
        p_ri = *reinterpret_cast<const float4*>(&rot[NB * DIMH + rrow * DIMH + dk + ec0]);
    };

    v2f acc[4][2];   // [batch j][entity k]
    #pragma unroll
    for (int j = 0; j < 4; ++j)
        #pragma unroll
        for (int k = 0; k < 2; ++k) { acc[j][k].x = 0.f; acc[j][k].y = 0.f; }

    load_chunk(dbase);

    for (int c = 0; c < NC; ++c) {
        // ---- store prefetched regs to LDS
        {
            int c4 = tid & 7;
            #pragma unroll
            for (int it = 0; it < 2; ++it) {
                int row = (tid + it * 256) >> 3;
                v4f lo, hi;
                lo.x = pe_re[it].x; lo.y = pe_re[it].y; lo.z = pe_im[it].x; lo.w = pe_im[it].y;
                hi.x = pe_re[it].z; hi.y = pe_re[it].w; hi.z = pe_im[it].z; hi.w = pe_im[it].w;
                s_e[row][2 * c4]     = lo;
                s_e[row][2 * c4 + 1] = hi;
            }
            v4f lo, hi;
            lo.x = p_rr.x; lo.y = p_rr.y; lo.z = p_ri.x; lo.w = p_ri.y;
            hi.x = p_rr.z; hi.y = p_rr.w; hi.z = p_ri.z; hi.w = p_ri.w;
            s_r[rrow][2 * c4]     = lo;
            s_r[rrow][2 * c4 + 1] = hi;
        }
        __syncthreads();

        // ---- issue next chunk's global loads (consumed after next barrier)
        if (c + 1 < NC) load_chunk(dbase + (c + 1) * DK);

        #pragma unroll 4
        for (int p = 0; p < DK / 2; ++p) {
            v4f r4[4], e4[2];
            #pragma unroll
            for (int j = 0; j < 4; ++j) r4[j] = s_r[bg + j][p];
            #pragma unroll
            for (int k = 0; k < 2; ++k) e4[k] = s_e[eg + 32 * k][p];
            #pragma unroll
            for (int j = 0; j < 4; ++j)
                #pragma unroll
                for (int k = 0; k < 2; ++k) {
                    v2f a = r4[j].xy - e4[k].xy;   // re diff (packed)
                    v2f b = r4[j].zw - e4[k].zw;   // im diff (packed)
                    v2f s = a * a + b * b;         // v_pk_mul + v_pk_fma
                    acc[j][k] += sqrt2(s);         // v_pk_add
                }
        }
        __syncthreads();
    }

    #pragma unroll
    for (int k = 0; k < 2; ++k) {
        int e = eb + eg + 32 * k;
        if (e < E_TOT) {
            #pragma unroll
            for (int j = 0; j < 4; ++j) {
                float s = acc[j][k].x + acc[j][k].y;
                if (DIRECT) {
                    dst[(size_t)(bg + j) * E_TOT + e] = 6.0f - s;
                } else {
                    // partial sums: contention-free coalesced streaming stores
                    dst[(size_t)half * (NB * E_TOT) + (size_t)(bg + j) * E_TOT + e] = s;
                }
            }
        }
    }
}

// Kernel 3 (split mode): out = MARGIN - (p0 + p1), float4-vectorized.
__global__ __launch_bounds__(256) void reduce_kernel(const float* __restrict__ part,
                                                     float* __restrict__ out) {
    int i = blockIdx.x * 256 + threadIdx.x;
    if (i < (NB * E_TOT) / 4) {
        float4 a = reinterpret_cast<const float4*>(part)[i];
        float4 b = reinterpret_cast<const float4*>(part + (size_t)NB * E_TOT)[i];
        float4 o;
        o.x = 6.0f - (a.x + b.x);
        o.y = 6.0f - (a.y + b.y);
        o.z = 6.0f - (a.z + b.z);
        o.w = 6.0f - (a.w + b.w);
        reinterpret_cast<float4*>(out)[i] = o;
    }
}

extern "C" void kernel_launch(void* const* d_in, const int* in_sizes, int n_in,
                              void* d_out, int out_size, void* d_ws, size_t ws_size,
                              hipStream_t stream) {
    const float* head = (const float*)d_in[0];   // (32, 512)
    const float* rel  = (const float*)d_in[1];   // (32, 256)
    const float* ent  = (const float*)d_in[2];   // (43234, 512)
    float* rot  = (float*)d_ws;                       // 64 KB
    float* part = rot + 2 * NB * DIMH;                // 2 * 32 * 43234 floats = 11.07 MB

    rot_kernel<<<(NB * DIMH) / 256, 256, 0, stream>>>(head, rel, rot);

    const size_t need = (size_t)(2 * NB * DIMH) * 4 + (size_t)2 * NB * E_TOT * 4;
    const int etiles = (E_TOT + TE - 1) / TE;    // 676

    if (ws_size >= need) {
        dist_kernel<false><<<etiles * 2, 256, 0, stream>>>(ent, rot, part);
        int rblocks = ((NB * E_TOT) / 4 + 255) / 256;   // 1352
        reduce_kernel<<<rblocks, 256, 0, stream>>>(part, (float*)d_out);
    } else {
        dist_kernel<true><<<etiles, 256, 0, stream>>>(ent, rot, (float*)d_out);
    }
}

// Round 7
// 184.340 us; speedup vs baseline: 1.1443x; 1.1443x over previous
//
#include <hip/hip_runtime.h>
#include <math.h>

#define DIMH 256        // D
#define NB   32         // batch
#define E_TOT 43234
#define TE   64         // entities per block
#define DK   32         // d-chunk staged in LDS
#define NC   (DIMH / DK)  // 8 chunks
// reference: phase = rel / (REL_RANGE/PI); REL_RANGE/PI = 0.03125/PI
#define PHASE_DIV 0.009947183943243459f

typedef float v2f __attribute__((ext_vector_type(2)));

__device__ __forceinline__ unsigned bf16_rne(float f) {
    unsigned u = __float_as_uint(f);
    return (u + 0x7FFFu + ((u >> 16) & 1u)) >> 16;
}
__device__ __forceinline__ unsigned pack_bf16(float f0, float f1) {
    return bf16_rne(f0) | (bf16_rne(f1) << 16);
}
__device__ __forceinline__ v2f unpack_bf16(unsigned w) {
    v2f r;
    r.x = __uint_as_float(w << 16);
    r.y = __uint_as_float(w & 0xFFFF0000u);
    return r;
}

// Kernel 1: rotate head by relation phase; emit bf16-packed rot pairs.
// rot_bf[b*128 + dp] = { pack(re_rot[2dp], re_rot[2dp+1]), pack(im...) }
__global__ __launch_bounds__(256) void rot_kernel(const float* __restrict__ head,
                                                  const float* __restrict__ rel,
                                                  uint2* __restrict__ rot_bf) {
    int i  = blockIdx.x * 256 + threadIdx.x;   // 0..4095
    int b  = i >> 7;
    int dp = i & 127;
    int d0 = dp * 2;
    float re0, re1, im0, im1;
    {
        float re_h = head[b * 2 * DIMH + d0];
        float im_h = head[b * 2 * DIMH + DIMH + d0];
        float s, c;
        sincosf(rel[b * DIMH + d0] / PHASE_DIV, &s, &c);
        re0 = re_h * c - im_h * s;
        im0 = re_h * s + im_h * c;
    }
    {
        float re_h = head[b * 2 * DIMH + d0 + 1];
        float im_h = head[b * 2 * DIMH + DIMH + d0 + 1];
        float s, c;
        sincosf(rel[b * DIMH + d0 + 1] / PHASE_DIV, &s, &c);
        re1 = re_h * c - im_h * s;
        im1 = re_h * s + im_h * c;
    }
    uint2 w;
    w.x = pack_bf16(re0, re1);
    w.y = pack_bf16(im0, im1);
    rot_bf[b * (DIMH / 2) + dp] = w;
}

__device__ __forceinline__ v2f sqrt2(v2f s) {
    v2f r;
    r.x = __builtin_amdgcn_sqrtf(s.x);
    r.y = __builtin_amdgcn_sqrtf(s.y);
    return r;
}

// Kernel 2: block = 64-entity tile x all 256 d, all 32 batches. Direct output
// writes (no split/partials/atomics — R5/R6 showed the split structure blows
// up HBM traffic 2.3x; R2-style direct writes profile clean at 5.9 MB).
// LDS holds bf16 pairs: uint2 = (re_d0|re_d1, im_d0|im_d1) -> 3 B/contrib
// (half of R4's 6) attacking the measured ~40us LDS-BW floor.
// Row stride 17 uint2 = 34 words -> ent-read bank = 2*eg mod 32, 2 lanes per
// bank-pair on b64 = free (R2-verified family). rot reads are half-wave
// broadcasts. LDS total 13.3 KB.
__global__ __launch_bounds__(256, 4) void dist_kernel(const float* __restrict__ ent,
                                                      const uint2* __restrict__ rot_bf,
                                                      float* __restrict__ out) {
    __shared__ uint2 s_e[TE][DK / 2 + 1];   // 64 x 17 x 8 B = 8.7 KB
    __shared__ uint2 s_r[NB][DK / 2 + 1];   // 32 x 17 x 8 B = 4.5 KB

    const int tid = threadIdx.x;
    const int eb  = blockIdx.x * TE;
    const int eg  = tid & 31;          // entity group: rows eg, eg+32
    const int bg  = (tid >> 5) * 4;    // first of 4 batch rows

    // ent staging tasks: 512 = 64 rows x 8 col-quads; 2 per thread.
    const int row0 = tid >> 3;                 // 0..31
    const int row1 = (tid + 256) >> 3;         // 32..63
    const int c4   = tid & 7;                  // quad: d = dk + 4*c4
    const int er0  = min(eb + row0, E_TOT - 1);
    const int er1  = min(eb + row1, E_TOT - 1);
    // rot staging tasks: 512 uint2 = 32 rows x 16 pairs; 2 per thread.
    const int rrow0 = tid >> 4;                // 0..15
    const int rrow1 = (tid + 256) >> 4;        // 16..31
    const int rpp   = tid & 15;                // pair within chunk

    float4 pre[2], pim[2];
    uint2  prt[2];

    auto load_chunk = [&](int c) {
        const int dk = c * DK;
        const float* b0 = &ent[(size_t)er0 * (2 * DIMH)];
        const float* b1 = &ent[(size_t)er1 * (2 * DIMH)];
        pre[0] = *reinterpret_cast<const float4*>(b0 + dk + 4 * c4);
        pim[0] = *reinterpret_cast<const float4*>(b0 + DIMH + dk + 4 * c4);
        pre[1] = *reinterpret_cast<const float4*>(b1 + dk + 4 * c4);
        pim[1] = *reinterpret_cast<const float4*>(b1 + DIMH + dk + 4 * c4);
        prt[0] = rot_bf[rrow0 * (DIMH / 2) + c * (DK / 2) + rpp];
        prt[1] = rot_bf[rrow1 * (DIMH / 2) + c * (DK / 2) + rpp];
    };

    v2f acc[4][2];   // [batch j][entity k]
    #pragma unroll
    for (int j = 0; j < 4; ++j)
        #pragma unroll
        for (int k = 0; k < 2; ++k) { acc[j][k].x = 0.f; acc[j][k].y = 0.f; }

    load_chunk(0);

    for (int c = 0; c < NC; ++c) {
        // ---- convert prefetched regs to bf16 pairs, store to LDS
        {
            const int rows[2] = {row0, row1};
            #pragma unroll
            for (int it = 0; it < 2; ++it) {
                uint2 w0, w1;
                w0.x = pack_bf16(pre[it].x, pre[it].y);
                w0.y = pack_bf16(pim[it].x, pim[it].y);
                w1.x = pack_bf16(pre[it].z, pre[it].w);
                w1.y = pack_bf16(pim[it].z, pim[it].w);
                s_e[rows[it]][2 * c4]     = w0;
                s_e[rows[it]][2 * c4 + 1] = w1;
            }
            s_r[rrow0][rpp] = prt[0];
            s_r[rrow1][rpp] = prt[1];
        }
        __syncthreads();

        // ---- issue next chunk's global loads (consumed after next barrier)
        if (c + 1 < NC) load_chunk(c + 1);

        #pragma unroll 4
        for (int p = 0; p < DK / 2; ++p) {
            v2f rr[4], ri[4], er[2], ei[2];
            #pragma unroll
            for (int j = 0; j < 4; ++j) {
                uint2 w = s_r[bg + j][p];
                rr[j] = unpack_bf16(w.x);
                ri[j] = unpack_bf16(w.y);
            }
            #pragma unroll
            for (int k = 0; k < 2; ++k) {
                uint2 w = s_e[eg + 32 * k][p];
                er[k] = unpack_bf16(w.x);
                ei[k] = unpack_bf16(w.y);
            }
            #pragma unroll
            for (int j = 0; j < 4; ++j)
                #pragma unroll
                for (int k = 0; k < 2; ++k) {
                    v2f a = rr[j] - er[k];     // v_pk_add (neg)
                    v2f b = ri[j] - ei[k];
                    v2f s = a * a + b * b;     // v_pk_mul + v_pk_fma
                    acc[j][k] += sqrt2(s);     // v_pk_add
                }
        }
        __syncthreads();
    }

    #pragma unroll
    for (int k = 0; k < 2; ++k) {
        int e = eb + eg + 32 * k;
        if (e < E_TOT) {
            #pragma unroll
            for (int j = 0; j < 4; ++j)
                out[(size_t)(bg + j) * E_TOT + e] = 6.0f - (acc[j][k].x + acc[j][k].y);
        }
    }
}

extern "C" void kernel_launch(void* const* d_in, const int* in_sizes, int n_in,
                              void* d_out, int out_size, void* d_ws, size_t ws_size,
                              hipStream_t stream) {
    const float* head = (const float*)d_in[0];   // (32, 512)
    const float* rel  = (const float*)d_in[1];   // (32, 256)
    const float* ent  = (const float*)d_in[2];   // (43234, 512)
    uint2* rot_bf = (uint2*)d_ws;                // 32 * 128 * 8 B = 32 KB

    rot_kernel<<<(NB * DIMH / 2) / 256, 256, 0, stream>>>(head, rel, rot_bf);

    int etiles = (E_TOT + TE - 1) / TE;          // 676
    dist_kernel<<<etiles, 256, 0, stream>>>(ent, rot_bf, (float*)d_out);
}

// Round 8
// 174.805 us; speedup vs baseline: 1.2067x; 1.0546x over previous
//
#include <hip/hip_runtime.h>
#include <math.h>

#define DIMH 256        // D
#define NB   32         // batch
#define E_TOT 43234
#define TE   32         // entities per block  (1352 blocks = 5.28/CU)
#define DK   32         // d-chunk staged in LDS
#define NC   (DIMH / DK)  // 8 chunks
// reference: phase = rel / (REL_RANGE/PI); REL_RANGE/PI = 0.03125/PI
#define PHASE_DIV 0.009947183943243459f

typedef float v2f __attribute__((ext_vector_type(2)));
typedef float v4f __attribute__((ext_vector_type(4)));

// Kernel 1: rotate head by relation phase; emit rot directly in the
// interleaved v4f layout (re_2p, re_2p+1, im_2p, im_2p+1) per (b, dpair)
// so dist stages it with a single float4 load -> single LDS store.
__global__ __launch_bounds__(256) void rot_kernel(const float* __restrict__ head,
                                                  const float* __restrict__ rel,
                                                  float4* __restrict__ rot_v4) {
    int i  = blockIdx.x * 256 + threadIdx.x;   // 0..4095
    int b  = i >> 7;
    int dp = i & 127;
    int d0 = dp * 2;
    float4 w;
    {
        float re_h = head[b * 2 * DIMH + d0];
        float im_h = head[b * 2 * DIMH + DIMH + d0];
        float s, c;
        sincosf(rel[b * DIMH + d0] / PHASE_DIV, &s, &c);
        w.x = re_h * c - im_h * s;
        w.z = re_h * s + im_h * c;
    }
    {
        float re_h = head[b * 2 * DIMH + d0 + 1];
        float im_h = head[b * 2 * DIMH + DIMH + d0 + 1];
        float s, c;
        sincosf(rel[b * DIMH + d0 + 1] / PHASE_DIV, &s, &c);
        w.y = re_h * c - im_h * s;
        w.w = re_h * s + im_h * c;
    }
    rot_v4[b * (DIMH / 2) + dp] = w;
}

__device__ __forceinline__ v2f sqrt2(v2f s) {
    v2f r;
    r.x = __builtin_amdgcn_sqrtf(s.x);
    r.y = __builtin_amdgcn_sqrtf(s.y);
    return r;
}

// Kernel 2: block = 32-entity tile x all 256 d, all 32 batches.
// Finer e-split than R7 (TE 64->32): 1352 blocks = 5.28/CU = ~21 waves/CU —
// attacks the 19-23% occupancy ceiling every direct-mode round showed, with
// NO extra traffic (e-split reads each ent row exactly once; d-split in R5/R6
// tripled HBM bytes). Direct output stores, no partials/atomics.
// LDS element = v4f (re0,re1,im0,im1); row stride 17 float4 — the R4-verified
// ~0-conflict pattern. LDS 17.4 KB -> not resource-capped (grid-capped).
// Per-thread tile: 2 batch x 2 entity; 20 pk-VALU + 8 sqrt + 4 b128 per
// 8 contribs, zero unpack (R7 showed bf16 unpack costs more than bytes save).
__global__ __launch_bounds__(256, 6) void dist_kernel(const float* __restrict__ ent,
                                                      const float4* __restrict__ rot_v4,
                                                      float* __restrict__ out) {
    __shared__ v4f s_e[TE][DK / 2 + 1];   // 32 x 17 x 16 B = 8.7 KB
    __shared__ v4f s_r[NB][DK / 2 + 1];   // 32 x 17 x 16 B = 8.7 KB

    const int tid = threadIdx.x;
    const int eb  = blockIdx.x * TE;
    const int ep  = tid & 15;          // entities {ep, ep+16}
    const int bp  = tid >> 4;          // batches {2bp, 2bp+1}

    // ent staging: 256 tasks = 32 rows x 8 quads, 1 per thread (re+im loads)
    const int srow = tid >> 3;                 // 0..31
    const int c4   = tid & 7;                  // quad: d = dk + 4*c4
    const int er   = min(eb + srow, E_TOT - 1);
    // rot staging: 512 float4 = 32 rows x 16 dpairs, 2 per thread
    const int rrow = tid >> 4;                 // 0..15 (and +16)
    const int rdp  = tid & 15;                 // dpair within chunk

    float4 p_re, p_im, p_r0, p_r1;

    auto load_chunk = [&](int c) {
        const int dk = c * DK;
        const float* b0 = &ent[(size_t)er * (2 * DIMH)];
        p_re = *reinterpret_cast<const float4*>(b0 + dk + 4 * c4);
        p_im = *reinterpret_cast<const float4*>(b0 + DIMH + dk + 4 * c4);
        p_r0 = rot_v4[rrow * (DIMH / 2) + c * (DK / 2) + rdp];
        p_r1 = rot_v4[(rrow + 16) * (DIMH / 2) + c * (DK / 2) + rdp];
    };

    v2f acc[2][2];   // [batch j][entity k]
    #pragma unroll
    for (int j = 0; j < 2; ++j)
        #pragma unroll
        for (int k = 0; k < 2; ++k) { acc[j][k].x = 0.f; acc[j][k].y = 0.f; }

    load_chunk(0);

    for (int c = 0; c < NC; ++c) {
        // ---- store prefetched regs to LDS (interleave ent re/im into v4f)
        {
            v4f lo, hi;
            lo.x = p_re.x; lo.y = p_re.y; lo.z = p_im.x; lo.w = p_im.y;
            hi.x = p_re.z; hi.y = p_re.w; hi.z = p_im.z; hi.w = p_im.w;
            s_e[srow][2 * c4]     = lo;
            s_e[srow][2 * c4 + 1] = hi;
            v4f r0, r1;
            r0.x = p_r0.x; r0.y = p_r0.y; r0.z = p_r0.z; r0.w = p_r0.w;
            r1.x = p_r1.x; r1.y = p_r1.y; r1.z = p_r1.z; r1.w = p_r1.w;
            s_r[rrow][rdp]      = r0;
            s_r[rrow + 16][rdp] = r1;
        }
        __syncthreads();

        // ---- issue next chunk's global loads (consumed after next barrier)
        if (c + 1 < NC) load_chunk(c + 1);

        #pragma unroll 4
        for (int p = 0; p < DK / 2; ++p) {
            v4f r0 = s_r[2 * bp][p];
            v4f r1 = s_r[2 * bp + 1][p];
            v4f e0 = s_e[ep][p];
            v4f e1 = s_e[ep + 16][p];

            {   v2f a = r0.xy - e0.xy, b = r0.zw - e0.zw;
                acc[0][0] += sqrt2(a * a + b * b); }
            {   v2f a = r0.xy - e1.xy, b = r0.zw - e1.zw;
                acc[0][1] += sqrt2(a * a + b * b); }
            {   v2f a = r1.xy - e0.xy, b = r1.zw - e0.zw;
                acc[1][0] += sqrt2(a * a + b * b); }
            {   v2f a = r1.xy - e1.xy, b = r1.zw - e1.zw;
                acc[1][1] += sqrt2(a * a + b * b); }
        }
        __syncthreads();
    }

    #pragma unroll
    for (int k = 0; k < 2; ++k) {
        int e = eb + ep + 16 * k;
        if (e < E_TOT) {
            #pragma unroll
            for (int j = 0; j < 2; ++j)
                out[(size_t)(2 * bp + j) * E_TOT + e] = 6.0f - (acc[j][k].x + acc[j][k].y);
        }
    }
}

extern "C" void kernel_launch(void* const* d_in, const int* in_sizes, int n_in,
                              void* d_out, int out_size, void* d_ws, size_t ws_size,
                              hipStream_t stream) {
    const float* head = (const float*)d_in[0];   // (32, 512)
    const float* rel  = (const float*)d_in[1];   // (32, 256)
    const float* ent  = (const float*)d_in[2];   // (43234, 512)
    float4* rot_v4 = (float4*)d_ws;              // 32 * 128 * 16 B = 64 KB

    rot_kernel<<<(NB * DIMH / 2) / 256, 256, 0, stream>>>(head, rel, rot_v4);

    int etiles = (E_TOT + TE - 1) / TE;          // 1352
    dist_kernel<<<etiles, 256, 0, stream>>>(ent, rot_v4, (float*)d_out);
}